// Round 2
// 416.783 us; speedup vs baseline: 1.0314x; 1.0314x over previous
//
#include <hip/hip_runtime.h>
#include <hip/hip_bf16.h>

// BitLevelMapper: bits [B,16] int32 {0,1} (mem index j holds value bit 15-j),
// tables [16, 32768] float32 {0,1}. For bit i: addr = value of bits 0..i-1,
// flip = tables[i][addr], out bit i = bit i ^ flip. Output float32, reversed
// layout like input.
//
// R5 (prev session best, 428.9us): split compress/expand through an 8 MB
// intermediate. Counters show the timed window is dominated by 2x ~165us
// 1-GiB harness poison fills; our kernels are only ~100us of it.
// R6: fuse compress+expand into ONE pass (saves 16 MB intermediate + one
// launch). Historical fused plateau (163us, all pipes idle) was a latency
// chain: load->shfl->shfl->LDS->store serialized per tile. Here all 4
// global reads are issued nontemporally BEFORE the table-stage barrier so
// HBM latency hides under LDS staging; compute then runs on resident regs.
// R7: fix compile — __builtin_nontemporal_load needs a clang ext_vector
// type, not HIP_vector_type int4.

#define PACK_WORDS 2048   // 65536 bits (65535 used), 8 KB

typedef float vfloat4 __attribute__((ext_vector_type(4)));
typedef int   vint4   __attribute__((ext_vector_type(4)));

__global__ __launch_bounds__(256) void
pack_tables_kernel(const float* __restrict__ tables, unsigned* __restrict__ packed) {
    int g = blockIdx.x * blockDim.x + threadIdx.x;   // global bit index
    bool val = false;
    if (g < 65535) {
        int i = 31 - __clz(g + 1);            // row: (2^i - 1) <= g < (2^{i+1} - 1)
        int a = g - ((1 << i) - 1);           // address within row
        val = tables[i * 32768 + a] != 0.0f;
    }
    unsigned long long m = __ballot(val);
    if ((threadIdx.x & 63) == 0) {            // one writer per wave, 2 words
        packed[(g >> 5)]     = (unsigned)m;
        packed[(g >> 5) + 1] = (unsigned)(m >> 32);
    }
}

// Fused pass: bits (int32 {0,1}) -> float32 output, one trip through HBM.
// Lane t&3 = quarter q of row t>>2. Per iteration: int4 load (16B coalesced),
// quad OR-butterfly assembles the 16-bit row value v, 4 packed-table lookups
// from LDS, one float4 nt store (coalesced).
__global__ __launch_bounds__(256) void
fused_kernel(const vint4* __restrict__ bits4,
             const unsigned* __restrict__ packed,
             vfloat4* __restrict__ out4) {
    __shared__ unsigned tab[PACK_WORDS];
    {   // stage 8 KB table (512 int4 / 256 threads = 2 each)
        const vint4* p4 = (const vint4*)packed;
        vint4* t4 = (vint4*)tab;
        t4[threadIdx.x]       = p4[threadIdx.x];
        t4[threadIdx.x + 256] = p4[threadIdx.x + 256];
    }

    const size_t base = (size_t)blockIdx.x * 1024 + threadIdx.x;

    // Front-load ALL global reads before the barrier: HBM latency (~900cy)
    // overlaps the LDS staging + syncthreads instead of serializing with
    // the shuffle/lookup chain (the R0-R4 plateau suspect).
    vint4 m[4];
    #pragma unroll
    for (int it = 0; it < 4; ++it)
        m[it] = __builtin_nontemporal_load(&bits4[base + (size_t)it * 256]);

    __syncthreads();

    const int q4 = (int)(threadIdx.x & 3) << 2;      // 4*q, invariant
    #pragma unroll
    for (int it = 0; it < 4; ++it) {
        size_t t = base + (size_t)it * 256;
        // elem 0 = first in memory order = value bit 15-4q -> nib bit3
        unsigned nb = (unsigned)((m[it][0] << 3) | (m[it][1] << 2) |
                                 (m[it][2] << 1) |  m[it][3]);
        unsigned v = nb << (12 - q4);
        v |= (unsigned)__shfl_xor((int)v, 1, 64);
        v |= (unsigned)__shfl_xor((int)v, 2, 64);    // full 16-bit row value
        float o[4];
        #pragma unroll
        for (int j = 0; j < 4; ++j) {
            int i = 15 - q4 - j;                     // value bit for this slot
            unsigned mask = (1u << i) - 1u;
            unsigned bidx = mask + (v & mask);       // (2^i-1) + addr
            unsigned fl   = tab[bidx >> 5] >> (bidx & 31u);
            o[j] = (float)(((v >> i) ^ fl) & 1u);
        }
        vfloat4 f = {o[0], o[1], o[2], o[3]};
        __builtin_nontemporal_store(f, &out4[t]);
    }
}

extern "C" void kernel_launch(void* const* d_in, const int* in_sizes, int n_in,
                              void* d_out, int out_size, void* d_ws, size_t ws_size,
                              hipStream_t stream) {
    const int*   bits   = (const int*)d_in[0];
    const float* tables = (const float*)d_in[1];
    float*       out    = (float*)d_out;
    unsigned*    packed = (unsigned*)d_ws;   // 8 KB

    int nrows    = in_sizes[0] / 16;         // 4194304
    int nquarter = nrows * 4;                // 16777216

    pack_tables_kernel<<<65536 / 256, 256, 0, stream>>>(tables, packed);

    // 4 quarters/thread -> 1024 quarters/block
    fused_kernel<<<nquarter / 1024, 256, 0, stream>>>((const vint4*)bits, packed,
                                                      (vfloat4*)out);
}